// Round 17
// baseline (595.056 us; speedup 1.0000x reference)
//
#include <hip/hip_runtime.h>
#include <cstdint>

#define N_NODES 50000
#define N_EDGES 1200000
#define NP2 50176          // padded node count, multiple of 256, >= N_NODES+1
#define NSCAN 196          // NP2/256
#define BM 64              // rows per GEMM block
#define NWG 1564           // GT*2 output-pairs
#define NB 25              // buckets of 2048 nodes (dst>>11)
#define BCAP 52224         // per-bucket capacity (expect ~49152, +14 sigma)

typedef __attribute__((ext_vector_type(8))) short short8;   // 8 bf16 in 4 VGPRs
typedef __attribute__((ext_vector_type(4))) float f32x4;

__device__ __forceinline__ unsigned short f2bf(float x) {
    unsigned u = __float_as_uint(x);
    unsigned r = (u + 0x7FFFu + ((u >> 16) & 1u)) >> 16;   // RNE
    return (unsigned short)r;
}
__device__ __forceinline__ float bf2f(unsigned short h) {
    return __uint_as_float(((unsigned)h) << 16);
}
// LDS byte offset for [row][128 bf16] tiles with bank-conflict XOR swizzle (T2)
__device__ __forceinline__ int swz(int row, int kbyte) {
    return row * 256 + (kbyte ^ ((row & 7) << 4));
}

// ---------- prep: W[k][n] fp32 -> WT[n][k] bf16, 8 matrices ----------
__global__ __launch_bounds__(256) void prep_w(
    const float* __restrict__ W0, const float* __restrict__ W1,
    const float* __restrict__ W2, const float* __restrict__ W3,
    const float* __restrict__ W4, const float* __restrict__ W5,
    const float* __restrict__ W6, const float* __restrict__ W7,
    unsigned short* __restrict__ WTH)
{
    int g = blockIdx.x * 256 + threadIdx.x;          // 8*16384 threads
    int m = g >> 14, o = g & 16383;
    int n = o >> 7, k = o & 127;
    const float* W;
    switch (m) {
        case 0: W = W0; break; case 1: W = W1; break;
        case 2: W = W2; break; case 3: W = W3; break;
        case 4: W = W4; break; case 5: W = W5; break;
        case 6: W = W6; break; default: W = W7; break;
    }
    WTH[g] = f2bf(W[k * 128 + n]);
}

// ---------- GEMM via MFMA, bf16, B staged in LDS ----------
__global__ __launch_bounds__(256, 2) void gemm_mfma(
    const float* __restrict__ A, int nrows,
    const unsigned short* __restrict__ WT,
    const float* __restrict__ b0, const float* __restrict__ b1,
    const float* __restrict__ b2, const float* __restrict__ b3,
    float* __restrict__ O0, unsigned short* __restrict__ O1,
    unsigned short* __restrict__ O2, float* __restrict__ O3)
{
    __shared__ unsigned short As[BM * 128];      // 16 KB, swizzled rows
    __shared__ unsigned short Bs[2 * 128 * 128]; // 64 KB, swizzled rows

    // bijective XCD-chunked swizzle (m204): NWG=1564, q=195, r=4
    const int orig = blockIdx.x;
    const int xcd = orig & 7, lid = orig >> 3;
    const int wgid = ((xcd < 4) ? xcd * 196 : 784 + (xcd - 4) * 195) + lid;
    const int xt = wgid >> 1;      // row tile
    const int p  = wgid & 1;       // output pair
    const int row0 = xt * BM;
    const int t = threadIdx.x;

    // ---- stage A: 64x128 fp32 -> bf16 ----
    #pragma unroll
    for (int i = 0; i < 4; ++i) {
        int chunk = t + i * 256;
        int row = chunk >> 4, c8 = chunk & 15;
        int gr = row0 + row;
        float4 a0, a1;
        if (gr < nrows) {
            a0 = *(const float4*)(A + (size_t)gr * 128 + c8 * 8);
            a1 = *(const float4*)(A + (size_t)gr * 128 + c8 * 8 + 4);
        } else {
            a0 = make_float4(0.f, 0.f, 0.f, 0.f);
            a1 = a0;
        }
        short8 h;
        h[0] = f2bf(a0.x); h[1] = f2bf(a0.y); h[2] = f2bf(a0.z); h[3] = f2bf(a0.w);
        h[4] = f2bf(a1.x); h[5] = f2bf(a1.y); h[6] = f2bf(a1.z); h[7] = f2bf(a1.w);
        *(short8*)((char*)As + swz(row, c8 * 16)) = h;
    }
    // ---- stage B: 2 outputs x 128x128 bf16 ----
    #pragma unroll
    for (int i = 0; i < 16; ++i) {
        int chunk = t + i * 256;
        int o = chunk >> 11, n = (chunk >> 4) & 127, c8 = chunk & 15;
        short8 b = *(const short8*)(WT + ((size_t)(p * 2 + o) * 16384 + n * 128 + c8 * 8));
        *(short8*)((char*)Bs + o * 32768 + swz(n, c8 * 16)) = b;
    }
    __syncthreads();

    const int lane = t & 63;
    const int w    = t >> 6;
    const int o    = w & 1;         // which output of the pair
    const int rg2  = w >> 1;        // 32-row group (0/1)
    const int mi   = lane & 15;
    const int kg   = lane >> 4;     // 0..3

    f32x4 acc[2][8] = {};

    #pragma unroll
    for (int ks = 0; ks < 4; ++ks) {
        const int kb = ks * 64 + kg * 16;   // byte offset in row
        short8 a0 = *(const short8*)((char*)As + swz(rg2 * 32 + mi, kb));
        short8 a1 = *(const short8*)((char*)As + swz(rg2 * 32 + 16 + mi, kb));
        #pragma unroll
        for (int ct = 0; ct < 8; ++ct) {
            short8 b = *(const short8*)((char*)Bs + o * 32768 + swz(ct * 16 + mi, kb));
            acc[0][ct] = __builtin_amdgcn_mfma_f32_16x16x32_bf16(a0, b, acc[0][ct], 0, 0, 0);
            acc[1][ct] = __builtin_amdgcn_mfma_f32_16x16x32_bf16(a1, b, acc[1][ct], 0, 0, 0);
        }
    }

    const int out = p * 2 + o;
    const float* bptr = (out == 0) ? b0 : (out == 1) ? b1 : (out == 2) ? b2 : b3;
    const int g2 = lane >> 4;
    #pragma unroll
    for (int ct = 0; ct < 8; ++ct) {
        int col = ct * 16 + mi;
        float bias_v = bptr[col];
        #pragma unroll
        for (int tile = 0; tile < 2; ++tile) {
            #pragma unroll
            for (int r = 0; r < 4; ++r) {
                int grow = row0 + rg2 * 32 + tile * 16 + g2 * 4 + r;
                if (grow < nrows) {
                    float val = acc[tile][ct][r] + bias_v;
                    size_t idx = (size_t)grow * 128 + col;
                    if (out == 0)      O0[idx] = val;
                    else if (out == 1) O1[idx] = f2bf(val);
                    else if (out == 2) O2[idx] = f2bf(val);
                    else               O3[idx] = val;
                }
            }
        }
    }
}

// ---------- CSR build ----------
__global__ __launch_bounds__(256) void hist_k(const int* __restrict__ dst, int* __restrict__ deg)
{
    int e = blockIdx.x * 256 + threadIdx.x;
    if (e >= N_EDGES) return;
    atomicAdd(&deg[dst[e]], 1);
}

__global__ __launch_bounds__(256) void scan1_k(const int* __restrict__ deg, int* __restrict__ bsum)
{
    __shared__ int s[256];
    int t = threadIdx.x;
    s[t] = deg[blockIdx.x * 256 + t];
    __syncthreads();
    for (int off = 128; off > 0; off >>= 1) {
        if (t < off) s[t] += s[t + off];
        __syncthreads();
    }
    if (t == 0) bsum[blockIdx.x] = s[0];
}

__global__ __launch_bounds__(256) void scan2_k(const int* __restrict__ bsum, int* __restrict__ boff,
                                               int* __restrict__ rowptr)
{
    __shared__ int s[256];
    int t = threadIdx.x;
    int v = (t < NSCAN) ? bsum[t] : 0;
    s[t] = v;
    __syncthreads();
    for (int off = 1; off < 256; off <<= 1) {
        int v2 = (t >= off) ? s[t - off] : 0;
        __syncthreads();
        s[t] += v2;
        __syncthreads();
    }
    if (t < NSCAN) boff[t] = s[t] - v;          // exclusive
    if (t == 0) rowptr[N_NODES] = N_EDGES;
}

__global__ __launch_bounds__(256) void scan3_k(const int* __restrict__ deg, const int* __restrict__ boff,
                                               int* __restrict__ rowptr)
{
    __shared__ int s[256];
    int t = threadIdx.x;
    int i = blockIdx.x * 256 + t;
    int d = deg[i];
    s[t] = d;
    __syncthreads();
    for (int off = 1; off < 256; off <<= 1) {
        int v2 = (t >= off) ? s[t - off] : 0;
        __syncthreads();
        s[t] += v2;
        __syncthreads();
    }
    if (i < N_NODES) rowptr[i] = boff[blockIdx.x] + s[t] - d;   // exclusive prefix
}

__global__ __launch_bounds__(32) void init_tails(int* __restrict__ tail)
{
    int t = threadIdx.x;
    if (t < NB) tail[t] = t * BCAP;
}

// pass 1: bucket edges by dst>>11 into EBUF (int2 {src,dst}), block-aggregated appends
__global__ __launch_bounds__(256) void bucket1(
    const int* __restrict__ src, const int* __restrict__ dst,
    int* __restrict__ tail, int2* __restrict__ ebuf)
{
    __shared__ int hist[NB];
    __shared__ int base[NB];
    const int t = threadIdx.x;
    const int e = blockIdx.x * 256 + t;
    if (t < NB) hist[t] = 0;
    __syncthreads();
    int b = 0, myoff = 0, s = 0, d = 0;
    const bool valid = e < N_EDGES;
    if (valid) {
        s = src[e]; d = dst[e];
        b = d >> 11;
        myoff = atomicAdd(&hist[b], 1);
    }
    __syncthreads();
    if (t < NB && hist[t] > 0) base[t] = atomicAdd(&tail[t], hist[t]);
    __syncthreads();
    if (valid) ebuf[base[b] + myoff] = make_int2(s, d);
}

// pass 2: one block per bucket; per-node cursors in LDS; local scatter into ESRC
__global__ __launch_bounds__(256) void bucket2(
    const int2* __restrict__ ebuf, const int* __restrict__ tail,
    const int* __restrict__ rowptr, int* __restrict__ esrc)
{
    __shared__ int cur[2048];
    const int b = blockIdx.x;
    const int t = threadIdx.x;
    const int node0 = b << 11;
    #pragma unroll
    for (int i = t; i < 2048; i += 256)
        cur[i] = (node0 + i < N_NODES) ? rowptr[node0 + i] : 0;
    __syncthreads();
    const int cnt = tail[b] - b * BCAP;
    for (int e = t; e < cnt; e += 256) {
        int2 ed = ebuf[b * BCAP + e];
        int p = atomicAdd(&cur[ed.y - node0], 1);
        esrc[p] = ed.x;
    }
}

// ---------- fused edge+softmax+aggregate v2: edge-per-lane-group ----------
template<int H>
__global__ __launch_bounds__(256) void fused_attn(
    const float* __restrict__ Qm, const unsigned short* __restrict__ Km,
    const unsigned short* __restrict__ Vm, const float* __restrict__ Sm,
    const int* __restrict__ rowptr, const int* __restrict__ esrc,
    float* __restrict__ out, float scale)
{
    const int n = blockIdx.x * 4 + (threadIdx.x >> 6);   // 4 nodes/block, 1 wave each
    const int l = threadIdx.x & 63;
    const int i = l >> 3;                                 // sub-edge 0..7
    const int h = l & 7;                                  // channel block 0..7
    const int start = rowptr[n];
    const int cnt   = rowptr[n + 1] - start;

    float q[16];
    {
        const float4* qp = (const float4*)(Qm + (size_t)n * 128 + h * 16);
        #pragma unroll
        for (int r = 0; r < 4; ++r) {
            float4 v = qp[r];
            q[4*r+0] = v.x * scale; q[4*r+1] = v.y * scale;
            q[4*r+2] = v.z * scale; q[4*r+3] = v.w * scale;
        }
    }

    float acc[16];
    #pragma unroll
    for (int c = 0; c < 16; ++c) acc[c] = 0.f;
    float den = 0.f;

    for (int base = 0; base < cnt; base += 8) {
        const int ei = base + i;
        const bool valid = ei < cnt;
        const int s = esrc[start + (valid ? ei : 0)];
        const short8* kp = (const short8*)(Km + (size_t)s * 128 + h * 16);
        short8 k0 = kp[0], k1 = kp[1];
        const short8* vp = (const short8*)(Vm + (size_t)s * 128 + h * 16);
        short8 v0 = vp[0], v1 = vp[1];

        float d0 = 0.f, d1 = 0.f;           // two chains for ILP
        #pragma unroll
        for (int c = 0; c < 8; ++c) {
            d0 += bf2f((unsigned short)k0[c]) * q[c];
            d1 += bf2f((unsigned short)k1[c]) * q[8 + c];
        }
        float d = d0 + d1;
        if (H == 1) {                       // combine partials across h-lanes
            d += __shfl_xor(d, 1);
            d += __shfl_xor(d, 2);
            d += __shfl_xor(d, 4);
        }
        float ea = valid ? __expf(d) : 0.f;
        den += ea;
        #pragma unroll
        for (int c = 0; c < 8; ++c) {
            acc[c]     += ea * bf2f((unsigned short)v0[c]);
            acc[8 + c] += ea * bf2f((unsigned short)v1[c]);
        }
    }

    // reduce over sub-edge lanes (i): XOR masks 8,16,32
    #pragma unroll
    for (int m = 8; m <= 32; m <<= 1) {
        den += __shfl_xor(den, m);
        #pragma unroll
        for (int c = 0; c < 16; ++c) acc[c] += __shfl_xor(acc[c], m);
    }

    if (l < 8) {                            // i==0 lanes, h==l: write channels [16h,16h+16)
        float rd = 1.f / (den + 1e-16f);
        const float4* sp = (const float4*)(Sm + (size_t)n * 128 + l * 16);
        float4*       op = (float4*)(out + (size_t)n * 128 + l * 16);
        #pragma unroll
        for (int r = 0; r < 4; ++r) {
            float4 sv = sp[r];
            float4 ov;
            ov.x = acc[4*r+0] * rd + sv.x;
            ov.y = acc[4*r+1] * rd + sv.y;
            ov.z = acc[4*r+2] * rd + sv.z;
            ov.w = acc[4*r+3] * rd + sv.w;
            op[r] = ov;
        }
    }
}

// ---------- launch ----------
extern "C" void kernel_launch(void* const* d_in, const int* in_sizes, int n_in,
                              void* d_out, int out_size, void* d_ws, size_t ws_size,
                              hipStream_t stream)
{
    const float* x       = (const float*)d_in[0];
    const int*   ei      = (const int*)d_in[1];
    const int*   esrc_in = ei;                 // edge_index[0] = src
    const int*   edst_in = ei + N_EDGES;       // edge_index[1] = dst

    const float* Wq1 = (const float*)d_in[2];  const float* bq1 = (const float*)d_in[3];
    const float* Wk1 = (const float*)d_in[4];  const float* bk1 = (const float*)d_in[5];
    const float* Wv1 = (const float*)d_in[6];  const float* bv1 = (const float*)d_in[7];
    const float* Ws1 = (const float*)d_in[8];  const float* bs1 = (const float*)d_in[9];
    const float* Wq2 = (const float*)d_in[10]; const float* bq2 = (const float*)d_in[11];
    const float* Wk2 = (const float*)d_in[12]; const float* bk2 = (const float*)d_in[13];
    const float* Wv2 = (const float*)d_in[14]; const float* bv2 = (const float*)d_in[15];
    const float* Ws2 = (const float*)d_in[16]; const float* bs2 = (const float*)d_in[17];

    float* out = (float*)d_out;

    // workspace layout (bytes)
    char* base = (char*)d_ws;
    const size_t NF4 = (size_t)N_NODES * 128 * 4;   // 25.6 MB
    const size_t NF2 = (size_t)N_NODES * 128 * 2;   // 12.8 MB
    size_t off = 0;
    float*          Q    = (float*)(base + off);          off += NF4;
    float*          S    = (float*)(base + off);          off += NF4;
    unsigned short* Kb   = (unsigned short*)(base + off); off += NF2;
    unsigned short* Vb   = (unsigned short*)(base + off); off += NF2;
    unsigned short* WTH  = (unsigned short*)(base + off); off += 8 * 16384 * 2;
    int*            DEG  = (int*)(base + off);            off += (size_t)NP2 * 4;
    int*            ROW  = (int*)(base + off);            off += (size_t)NP2 * 4;
    int*            BSUM = (int*)(base + off);            off += 1024;
    int*            BOFF = (int*)(base + off);            off += 1024;
    int*            TAIL = (int*)(base + off);            off += 256;
    int*            ESRC = (int*)(base + off);            off += (size_t)N_EDGES * 4;
    int2*           EBUF = (int2*)(base + off);           off += (size_t)NB * BCAP * 8;
    if (ws_size < off) return;

    const int EB1 = (N_EDGES + 255) / 256;     // 4688
    const int FB  = N_NODES / 4;               // 12500

    hipMemsetAsync(DEG, 0, (size_t)NP2 * 4, stream);

    // weight prep (both layers): order Q1,K1,V1,S1,Q2,K2,V2,S2
    prep_w<<<512, 256, 0, stream>>>(Wq1, Wk1, Wv1, Ws1, Wq2, Wk2, Wv2, Ws2, WTH);

    // CSR by destination (shared by both layers), write-local bucketed build
    init_tails<<<1, 32, 0, stream>>>(TAIL);
    hist_k<<<EB1, 256, 0, stream>>>(edst_in, DEG);
    bucket1<<<EB1, 256, 0, stream>>>(esrc_in, edst_in, TAIL, EBUF);
    scan1_k<<<NSCAN, 256, 0, stream>>>(DEG, BSUM);
    scan2_k<<<1, 256, 0, stream>>>(BSUM, BOFF, ROW);
    scan3_k<<<NSCAN, 256, 0, stream>>>(DEG, BOFF, ROW);
    bucket2<<<NB, 256, 0, stream>>>(EBUF, TAIL, ROW, ESRC);

    // ---- layer 1: heads=8, ch=16 ----
    gemm_mfma<<<NWG, 256, 0, stream>>>(x, N_NODES, WTH,
        bq1, bk1, bv1, bs1, Q, Kb, Vb, S);
    fused_attn<8><<<FB, 256, 0, stream>>>(Q, Kb, Vb, S, ROW, ESRC, out, 0.25f);

    // ---- layer 2: heads=1, ch=128 ----
    gemm_mfma<<<NWG, 256, 0, stream>>>(out, N_NODES, WTH + 4 * 16384,
        bq2, bk2, bv2, bs2, Q, Kb, Vb, S);
    fused_attn<1><<<FB, 256, 0, stream>>>(Q, Kb, Vb, S, ROW, ESRC, out, 0.08838834764831845f);
}